// Round 3
// baseline (318.137 us; speedup 1.0000x reference)
//
#include <hip/hip_runtime.h>
#include <math.h>

#define TILE_PX 1280   // pixels per channel-pair tile (analysis worst-case: 119 rows x 10 cols = 1190)
#define MAXS 10        // ceil((TILE_PX/2)/64) pixel-pair slots per lane

__global__ __launch_bounds__(128) void pooler_kernel(
    const float* __restrict__ f0, const float* __restrict__ f1,
    const float* __restrict__ f2, const float* __restrict__ f3,
    const float* __restrict__ boxes, const int* __restrict__ bidx,
    float* __restrict__ out, int N)
{
  __shared__ __align__(16) float tile[2][TILE_PX * 2];  // [wave][pixel*2 + ch]
  const int tid  = threadIdx.x;
  const int wave = tid >> 6, lane = tid & 63;
  const int n    = blockIdx.y;
  if (n >= N) return;

  // ---- per-box meta (wave-uniform, recomputed by every lane) ----
  const float bx1 = boxes[4*n+0], by1 = boxes[4*n+1];
  const float bx2 = boxes[4*n+2], by2 = boxes[4*n+3];
  const float area = (bx2 - bx1 + 1.0f) * (by2 - by1 + 1.0f);
  const float s    = sqrtf(area);
  int lvl = (int)floorf(4.0f + log2f(s / 224.0f + 1e-6f));
  lvl = lvl < 2 ? 2 : (lvl > 5 ? 5 : lvl);
  const int li = lvl - 2;

  int H, W; const float* feat; float scale;
  switch (li) {
    case 0:  feat = f0; H = 200; W = 304; scale = 0.25f;    break;
    case 1:  feat = f1; H = 100; W = 152; scale = 0.125f;   break;
    case 2:  feat = f2; H = 50;  W = 76;  scale = 0.0625f;  break;
    default: feat = f3; H = 25;  W = 38;  scale = 0.03125f; break;
  }
  const int b = bidx[n];
  const float x1s = bx1 * scale, y1s = by1 * scale;
  const float roiw = fmaxf(bx2 * scale - x1s, 1.0f);
  const float roih = fmaxf(by2 * scale - y1s, 1.0f);
  const float binw = roiw / 7.0f, binh = roih / 7.0f;
  const float Hm1f = (float)(H - 1), Wm1f = (float)(W - 1);
  const int   Hm1  = H - 1,          Wm1  = W - 1;

  // ---- staged region (samples monotone: first g=0.25, last g=6.75) ----
  const float yA = fminf(fmaxf(y1s + binh * 0.25f, 0.0f), Hm1f);
  const float yB = fminf(fmaxf(y1s + binh * 6.75f, 0.0f), Hm1f);
  const float xA = fminf(fmaxf(x1s + binw * 0.25f, 0.0f), Wm1f);
  const float xB = fminf(fmaxf(x1s + binw * 6.75f, 0.0f), Wm1f);
  const int y_lo = (int)yA;
  const int y_hi = min((int)yB + 1, Hm1);
  const int regH = y_hi - y_lo + 1;
  const int x_lo = ((int)xA) & ~1;             // even -> 8B-aligned pair loads
  const int x_hi = min((int)xB + 1, Wm1);
  int regW = x_hi - x_lo + 1;
  regW += (regW & 1);   // even; W even + x_lo even => x_lo+regW-1 <= Wm1 always
  int npx = regH * regW;
  if (npx > TILE_PX) npx = TILE_PX;            // safety, never expected
  const int npair = npx >> 1;

  // ---- per-lane 16 corner weights + LDS byte offsets (channel-invariant) ----
  const int bin = (lane < 49) ? lane : 0;
  const int ph = bin / 7, pw = bin - (bin / 7) * 7;
  int   rT[2], rB[2], c0[2], c1[2];
  float hy[2], ly[2], vy[2], hx[2], lx[2], vx[2];
#pragma unroll
  for (int t = 0; t < 2; ++t) {
    const float gy = (float)ph + 0.25f + 0.5f * (float)t;
    const float Yf = y1s + binh * gy;
    vy[t] = (Yf >= -1.0f && Yf <= (float)H) ? 1.0f : 0.0f;
    const float y  = fminf(fmaxf(Yf, 0.0f), Hm1f);
    const int  y0  = (int)y;
    ly[t] = y - (float)y0;  hy[t] = 1.0f - ly[t];
    rT[t] = y0 - y_lo;
    rB[t] = min(y0 + 1, Hm1) - y_lo;

    const float gx = (float)pw + 0.25f + 0.5f * (float)t;
    const float Xf = x1s + binw * gx;
    vx[t] = (Xf >= -1.0f && Xf <= (float)W) ? 1.0f : 0.0f;
    const float x  = fminf(fmaxf(Xf, 0.0f), Wm1f);
    const int  x0  = (int)x;
    lx[t] = x - (float)x0;  hx[t] = 1.0f - lx[t];
    c0[t] = x0 - x_lo;
    c1[t] = min(x0 + 1, Wm1) - x_lo;
  }
  float wgt[16]; int ads[16];
#pragma unroll
  for (int sy = 0; sy < 2; ++sy)
#pragma unroll
    for (int sx = 0; sx < 2; ++sx) {
      const int   kk   = (sy * 2 + sx) * 4;
      const float base = vy[sy] * vx[sx] * 0.25f;
      wgt[kk+0] = hy[sy] * hx[sx] * base;  ads[kk+0] = (rT[sy]*regW + c0[sx]) * 8;
      wgt[kk+1] = hy[sy] * lx[sx] * base;  ads[kk+1] = (rT[sy]*regW + c1[sx]) * 8;
      wgt[kk+2] = ly[sy] * hx[sx] * base;  ads[kk+2] = (rB[sy]*regW + c0[sx]) * 8;
      wgt[kk+3] = ly[sy] * lx[sx] * base;  ads[kk+3] = (rB[sy]*regW + c1[sx]) * 8;
    }
#pragma unroll
  for (int kk = 0; kk < 16; ++kk)              // LDS-OOB clamp (paranoia only)
    ads[kk] = min(ads[kk], (TILE_PX * 2 - 2) * 4);

  // ---- per-lane staging offsets (channel-invariant, region-linear -> plane) ----
  int goff[MAXS];
#pragma unroll
  for (int s2 = 0; s2 < MAXS; ++s2) {
    const int pi = lane + (s2 << 6);           // pixel-pair index
    if (pi < npair) {
      const int p = pi << 1;
      const int r = p / regW;
      goff[s2] = r * W + (p - r * regW);
    } else goff[s2] = -1;
  }

  // ---- channel-pair loop: stage 2 planes -> interleaved tile, compute ----
  const size_t planeHW = (size_t)H * W;
  const int    cbase   = (blockIdx.x << 5) + (wave << 4);  // 16 ch per wave
  const float* pA   = feat + ((size_t)(b * 256 + cbase)) * planeHW
                           + (size_t)y_lo * W + x_lo;
  float*       outp = out + ((size_t)n * 256 + cbase) * 49 + lane;
  float*       myt  = tile[wave];

  for (int cc = 0; cc < 8; ++cc) {
    const float* p0 = pA;
    const float* p1 = pA + planeHW;
    float2 va[MAXS], vb[MAXS];
#pragma unroll
    for (int s2 = 0; s2 < MAXS; ++s2)
      if (goff[s2] >= 0) {
        va[s2] = *(const float2*)(p0 + goff[s2]);
        vb[s2] = *(const float2*)(p1 + goff[s2]);
      }
#pragma unroll
    for (int s2 = 0; s2 < MAXS; ++s2)
      if (goff[s2] >= 0) {
        const float4 q = make_float4(va[s2].x, vb[s2].x, va[s2].y, vb[s2].y);
        *(float4*)&myt[(lane + (s2 << 6)) << 2] = q;   // linear: conflict-free
      }
    __builtin_amdgcn_wave_barrier();   // compile-time ordering fence (0 cyc)

    if (lane < 49) {
      float a0 = 0.0f, a1 = 0.0f;
#pragma unroll
      for (int kk = 0; kk < 16; ++kk) {
        const float2 v = *(const float2*)((const char*)myt + ads[kk]);
        a0 = fmaf(wgt[kk], v.x, a0);
        a1 = fmaf(wgt[kk], v.y, a1);
      }
      outp[0]  = a0;
      outp[49] = a1;
    }
    __builtin_amdgcn_wave_barrier();
    pA   += 2 * planeHW;
    outp += 98;
  }
}

extern "C" void kernel_launch(void* const* d_in, const int* in_sizes, int n_in,
                              void* d_out, int out_size, void* d_ws, size_t ws_size,
                              hipStream_t stream) {
  const float* f0    = (const float*)d_in[0];
  const float* f1    = (const float*)d_in[1];
  const float* f2    = (const float*)d_in[2];
  const float* f3    = (const float*)d_in[3];
  const float* boxes = (const float*)d_in[4];
  const int*   bidx  = (const int*)d_in[5];
  const int N = in_sizes[5];                 // 1024 boxes
  dim3 grid(8, N);                           // 8 groups x (2 waves x 16 ch) = 256 ch
  pooler_kernel<<<grid, 128, 0, stream>>>(f0, f1, f2, f3, boxes, bidx,
                                          (float*)d_out, N);
}

// Round 4
// 283.012 us; speedup vs baseline: 1.1241x; 1.1241x over previous
//
#include <hip/hip_runtime.h>
#include <math.h>

#define TC4  288       // float4 chunks per buffer (vec path); analysis worst ~270
#define TFL  (TC4*4)   // floats per buffer = 1152 (4608 B)
#define MAXS 5         // staging slots per lane

typedef __attribute__((address_space(3))) void lds_void;
typedef const __attribute__((address_space(1))) void g_void;

__device__ __forceinline__ void dma16(const float* g, float* l) {
  __builtin_amdgcn_global_load_lds((g_void*)g, (lds_void*)l, 16, 0, 0);
}
__device__ __forceinline__ void dma4(const float* g, float* l) {
  __builtin_amdgcn_global_load_lds((g_void*)g, (lds_void*)l, 4, 0, 0);
}
__device__ __forceinline__ void waitvm() {
  asm volatile("s_waitcnt vmcnt(0)" ::: "memory");
}

__global__ __launch_bounds__(128) void pooler_kernel(
    const float* __restrict__ f0, const float* __restrict__ f1,
    const float* __restrict__ f2, const float* __restrict__ f3,
    const float* __restrict__ boxes, const int* __restrict__ bidx,
    float* __restrict__ out, int N)
{
  __shared__ __align__(16) float tiles[2][2][TFL];  // [wave][buf]
  __shared__ int rowlist[2][32];                    // deduped rows per wave
  const int tid  = threadIdx.x;
  const int wave = tid >> 6, lane = tid & 63;
  const int n    = blockIdx.y;
  if (n >= N) return;

  // ---- per-box meta (wave-uniform) ----
  const float bx1 = boxes[4*n+0], by1 = boxes[4*n+1];
  const float bx2 = boxes[4*n+2], by2 = boxes[4*n+3];
  const float area = (bx2 - bx1 + 1.0f) * (by2 - by1 + 1.0f);
  const float s    = sqrtf(area);
  int lvl = (int)floorf(4.0f + log2f(s / 224.0f + 1e-6f));
  lvl = lvl < 2 ? 2 : (lvl > 5 ? 5 : lvl);
  const int li = lvl - 2;

  int H, W; const float* feat; float scale;
  switch (li) {
    case 0:  feat = f0; H = 200; W = 304; scale = 0.25f;    break;
    case 1:  feat = f1; H = 100; W = 152; scale = 0.125f;   break;
    case 2:  feat = f2; H = 50;  W = 76;  scale = 0.0625f;  break;
    default: feat = f3; H = 25;  W = 38;  scale = 0.03125f; break;
  }
  const int b = bidx[n];
  const float x1s = bx1 * scale, y1s = by1 * scale;
  const float roiw = fmaxf(bx2 * scale - x1s, 1.0f);
  const float roih = fmaxf(by2 * scale - y1s, 1.0f);
  const float binw = roiw / 7.0f, binh = roih / 7.0f;
  const float Hm1f = (float)(H - 1), Wm1f = (float)(W - 1);
  const int   Hm1  = H - 1,          Wm1  = W - 1;
  const bool  vec  = (li != 3);            // levels 0-2: W%4==0, 16B DMA

  // ---- x extent (contiguous cols) ----
  const float xA = fminf(fmaxf(x1s + binw * 0.25f, 0.0f), Wm1f);
  const float xB = fminf(fmaxf(x1s + binw * 6.75f, 0.0f), Wm1f);
  const int x_lo  = (int)xA;
  const int x_lo4 = x_lo & ~3;
  const int x_hi  = min((int)xB + 1, Wm1);
  int row4 = (x_hi - x_lo4 + 4) >> 2;      // float4s per row (vec)
  row4 |= 1;                                // odd -> bank-spread row stride
  const int regW    = x_hi - x_lo + 1;      // floats per row (scalar)
  const int colbase = vec ? x_lo4 : x_lo;
  const int rs_f    = vec ? (row4 << 2) : regW;  // tile row stride (floats)
  const int rs_c    = vec ? row4 : regW;         // tile row stride (chunks)
  const size_t planeHW = (size_t)H * W;

  // ---- y sample dedup: rowlist + this lane's row->slot map ----
  const int bin = (lane < 49) ? lane : 0;
  const int ph = bin / 7, pw = bin - (bin / 7) * 7;
  const int iA = 2 * ph, iB = iA + 1;
  int sT[2], sB[2];
  int R;
  {
    int cnt = -1, prev = -1;
    for (int i = 0; i < 14; ++i) {
      const float g  = (float)(i >> 1) + 0.25f + 0.5f * (float)(i & 1);
      const float Yf = y1s + binh * g;
      const float y  = fminf(fmaxf(Yf, 0.0f), Hm1f);
      const int  y0  = (int)y;
      const int  y1i = min(y0 + 1, Hm1);
      if (y0 > prev)  { ++cnt; prev = y0;  rowlist[wave][cnt] = y0; }
      const int s0q = cnt - (prev - y0);    // rows prev-1,prev @ slots cnt-1,cnt
      if (y1i > prev) { ++cnt; prev = y1i; rowlist[wave][cnt] = y1i; }
      const int s1q = cnt - (prev - y1i);
      if (i == iA) { sT[0] = s0q; sB[0] = s1q; }
      if (i == iB) { sT[1] = s0q; sB[1] = s1q; }
    }
    R = cnt + 1;                            // <= 28
  }

  // ---- per-lane staging offsets (channel-invariant) ----
  int goffA[MAXS];
  {
    int cntc = R * rs_c;
    const int cap = vec ? TC4 : (MAXS * 64);
    if (cntc > cap) cntc = cap;             // paranoia; analysis: never hit
    for (int i2 = 0; i2 < MAXS; ++i2) {
      const int u = lane + (i2 << 6);
      if (u < cntc) {
        const int k = u / rs_c, c = u - k * rs_c;
        const int row = rowlist[wave][k];
        int off = row * W + colbase + (vec ? (c << 2) : c);
        off = min(off, (int)planeHW - (vec ? 4 : 1));   // stay in-plane
        goffA[i2] = off;
      } else goffA[i2] = -1;
    }
  }

  // ---- per-lane weights ----
  float hy[2], ly[2], vy[2], hx[2], lx[2], vx[2];
  int   c0[2], c1[2];
#pragma unroll
  for (int t = 0; t < 2; ++t) {
    const float gy = (float)ph + 0.25f + 0.5f * (float)t;
    const float Yf = y1s + binh * gy;
    vy[t] = (Yf >= -1.0f && Yf <= (float)H) ? 1.0f : 0.0f;
    const float y  = fminf(fmaxf(Yf, 0.0f), Hm1f);
    ly[t] = y - (float)((int)y);  hy[t] = 1.0f - ly[t];

    const float gx = (float)pw + 0.25f + 0.5f * (float)t;
    const float Xf = x1s + binw * gx;
    vx[t] = (Xf >= -1.0f && Xf <= (float)W) ? 1.0f : 0.0f;
    const float x  = fminf(fmaxf(Xf, 0.0f), Wm1f);
    const int  x0  = (int)x;
    lx[t] = x - (float)x0;  hx[t] = 1.0f - lx[t];
    c0[t] = x0 - colbase;
    c1[t] = min(x0 + 1, Wm1) - colbase;
  }
  float wgt[16]; int ads[16];
#pragma unroll
  for (int sy = 0; sy < 2; ++sy) {
    const int rT = sT[sy] * rs_f, rB = sB[sy] * rs_f;
#pragma unroll
    for (int sx = 0; sx < 2; ++sx) {
      const int   kk   = (sy * 2 + sx) * 4;
      const float base = vy[sy] * vx[sx] * 0.25f;
      wgt[kk+0] = hy[sy] * hx[sx] * base;  ads[kk+0] = rT + c0[sx];
      wgt[kk+1] = hy[sy] * lx[sx] * base;  ads[kk+1] = rT + c1[sx];
      wgt[kk+2] = ly[sy] * hx[sx] * base;  ads[kk+2] = rB + c0[sx];
      wgt[kk+3] = ly[sy] * lx[sx] * base;  ads[kk+3] = rB + c1[sx];
    }
  }
#pragma unroll
  for (int kk = 0; kk < 16; ++kk)
    ads[kk] = min(max(ads[kk], 0), TFL - 1);   // paranoia only

  // ---- channel loop: DMA double-buffer, zero barriers ----
  const int    cbase = (blockIdx.x << 5) + (wave << 4);   // 16 ch per wave
  const float* pl    = feat + ((size_t)(b * 256 + cbase)) * planeHW;
  float*       op    = out + ((size_t)n * 256 + cbase) * 49 + lane;
  float* const tb0   = &tiles[wave][0][0];
  float* const tb1   = &tiles[wave][1][0];

  auto stage = [&](const float* plane, float* tb) {
    if (vec) {
#pragma unroll
      for (int i2 = 0; i2 < MAXS; ++i2)
        if (goffA[i2] >= 0) dma16(plane + goffA[i2], tb + (i2 << 8));
    } else {
#pragma unroll
      for (int i2 = 0; i2 < MAXS; ++i2)
        if (goffA[i2] >= 0) dma4(plane + goffA[i2], tb + (i2 << 6));
    }
  };
  auto compute = [&](const float* tb, float* o) {
    if (lane < 49) {
      float acc = 0.0f;
#pragma unroll
      for (int kk = 0; kk < 16; ++kk)
        acc = fmaf(wgt[kk], tb[ads[kk]], acc);
      *o = acc;
    }
  };

  stage(pl, tb0);                               // ch 0
  for (int cp = 0; cp < 8; ++cp) {
    waitvm();                                   // ch 2cp staged
    stage(pl + planeHW, tb1);                   // prefetch ch 2cp+1
    compute(tb0, op);  op += 49;
    waitvm();                                   // ch 2cp+1 staged
    if (cp < 7) stage(pl + 2 * planeHW, tb0);   // prefetch ch 2cp+2
    compute(tb1, op);  op += 49;
    pl += 2 * planeHW;
  }
}

extern "C" void kernel_launch(void* const* d_in, const int* in_sizes, int n_in,
                              void* d_out, int out_size, void* d_ws, size_t ws_size,
                              hipStream_t stream) {
  const float* f0    = (const float*)d_in[0];
  const float* f1    = (const float*)d_in[1];
  const float* f2    = (const float*)d_in[2];
  const float* f3    = (const float*)d_in[3];
  const float* boxes = (const float*)d_in[4];
  const int*   bidx  = (const int*)d_in[5];
  const int N = in_sizes[5];                 // 1024 boxes
  dim3 grid(8, N);                           // 8 groups x (2 waves x 16 ch)
  pooler_kernel<<<grid, 128, 0, stream>>>(f0, f1, f2, f3, boxes, bidx,
                                          (float*)d_out, N);
}